// Round 19
// baseline (152.475 us; speedup 1.0000x reference)
//
#include <hip/hip_runtime.h>
#include <hip/hip_bf16.h>

typedef _Float16 f16x8 __attribute__((ext_vector_type(8)));
typedef _Float16 f16x4 __attribute__((ext_vector_type(4)));
typedef float f32x4 __attribute__((ext_vector_type(4)));
typedef float f32x16 __attribute__((ext_vector_type(16)));
typedef unsigned int u32;
typedef u32 u32x4 __attribute__((ext_vector_type(4)));

#define LOG2E 1.4426950408889634f

#if __has_builtin(__builtin_amdgcn_exp2f)
#define EXP2(x) __builtin_amdgcn_exp2f(x)
#else
__device__ inline float EXP2(float x) { float r; asm("v_exp_f32 %0, %1\n\ts_nop 0" : "=v"(r) : "v"(x)); return r; }
#endif

// B=16, C=512, HEAD=8, D=64, N=1024 (W=H=32)

__device__ inline void gll16(const void* g, void* l) {
  __builtin_amdgcn_global_load_lds(
      (const __attribute__((address_space(1))) void*)g,
      (__attribute__((address_space(3))) void*)l, 16, 0, 0);
}

// ---------------- transpose + prep fused ----------------
__global__ __launch_bounds__(256) void transpose_prep_kernel(
    const float* __restrict__ x, _Float16* __restrict__ Xt,
    const float* __restrict__ Wq, const float* __restrict__ Wk, const float* __restrict__ Wv,
    const float* __restrict__ rel_h, const float* __restrict__ rel_w,
    _Float16* __restrict__ Wall, _Float16* __restrict__ post) {
  __shared__ float tl[64][65];
  int bid = blockIdx.x;
  int b = bid >> 7;
  int rem = bid & 127;
  int c0 = (rem >> 4) * 64;
  int n0 = (rem & 15) * 64;
  int t = threadIdx.x;
#pragma unroll
  for (int p = 0; p < 16; ++p) {
    int idx = p * 256 + t;
    int i = idx >> 6, j = idx & 63;
    tl[i][j] = x[((size_t)b * 512 + c0 + i) * 1024 + n0 + j];
  }
  __syncthreads();
#pragma unroll
  for (int p = 0; p < 16; ++p) {
    int idx = p * 256 + t;
    int j = idx >> 6, i = idx & 63;
    Xt[((size_t)b * 1024 + n0 + j) * 512 + c0 + i] = (_Float16)tl[i][j];
  }
  for (int idx = bid * 256 + t; idx < 1310720; idx += 524288) {
    if (idx < 1536 * 512) {
      int o = idx >> 9;
      float wv;
      if (o < 512) wv = Wq[idx];
      else if (o < 1024) wv = Wk[idx - 512 * 512];
      else wv = Wv[idx - 1024 * 512];
      Wall[idx] = (_Float16)wv;
    } else {
      int p = idx - 1536 * 512;            // [0, 8*1024*64)
      int h = p >> 16;
      int rm = p & 65535;
      int n = rm >> 6;
      int d = rm & 63;
      float v = rel_h[(h * 64 + d) * 32 + (n & 31)] + rel_w[(h * 64 + d) * 32 + (n >> 5)];
      post[p] = (_Float16)(v * LOG2E);
    }
  }
}

// ---------------- QKV projection GEMM (dbuf; nb-major order for Xt L2 reuse) --------
// writes Kext[b][h][n][0:64]=k*log2e, [64:128]=q ; v[b][h][d][n]  (f16)
__global__ __launch_bounds__(256) void qkv_gemm(
    const _Float16* __restrict__ Wall, const _Float16* __restrict__ Xt,
    const float* __restrict__ bq, const float* __restrict__ bk, const float* __restrict__ bv,
    _Float16* __restrict__ kext, _Float16* __restrict__ vv) {
  __shared__ _Float16 At[2][128 * 64];
  __shared__ _Float16 Bt[2][128 * 64];
  int bid = blockIdx.x;
  int nb = bid / 12, mb = bid - nb * 12;   // nb-major: 12 consecutive blocks share Xt tile
  int o0 = mb * 128, j0 = nb * 128;
  int t = threadIdx.x;
  int w = t >> 6, l = t & 63, lg = l >> 4, lc = l & 15;
  int wm = w >> 1, wn = w & 1;
  int mode = mb >> 2;  // 0=q, 1=k, 2=v (block-uniform)
  f32x4 acc[4][4];
#pragma unroll
  for (int a = 0; a < 4; ++a)
#pragma unroll
    for (int bb = 0; bb < 4; ++bb) acc[a][bb] = (f32x4){0.f, 0.f, 0.f, 0.f};

  auto stageg = [&](int bufi, int k0) {
#pragma unroll
    for (int p = 0; p < 4; ++p) {
      int li = p * 256 + t;            // 16B chunk index
      int row = li >> 3;               // tile row
      int colb = (li & 7) << 4;        // linear byte col in row
      int scol = (colb ^ ((row & 7) << 4)) >> 1;  // inverse-swizzled f16 col
      gll16(Wall + (size_t)(o0 + row) * 512 + k0 + scol, At[bufi] + (size_t)li * 8);
      gll16(Xt + (size_t)(j0 + row) * 512 + k0 + scol, Bt[bufi] + (size_t)li * 8);
    }
  };

  stageg(0, 0);
  asm volatile("s_waitcnt vmcnt(0)\n\ts_barrier" ::: "memory");
  for (int ks = 0; ks < 8; ++ks) {
    if (ks + 1 < 8) stageg((ks + 1) & 1, (ks + 1) * 64);
    const char* Ab = (const char*)At[ks & 1];
    const char* Bb = (const char*)Bt[ks & 1];
    if (mode < 2) {
#pragma unroll
      for (int kf = 0; kf < 2; ++kf) {
        int kbyte = kf * 64 + lg * 16;
        f16x8 af[4], bf[4];
#pragma unroll
        for (int mi = 0; mi < 4; ++mi) {
          int row = wm * 64 + mi * 16 + lc;
          af[mi] = *(const f16x8*)(Ab + row * 128 + (kbyte ^ ((row & 7) << 4)));
        }
#pragma unroll
        for (int ni = 0; ni < 4; ++ni) {
          int row = wn * 64 + ni * 16 + lc;
          bf[ni] = *(const f16x8*)(Bb + row * 128 + (kbyte ^ ((row & 7) << 4)));
        }
#pragma unroll
        for (int mi = 0; mi < 4; ++mi)
#pragma unroll
          for (int ni = 0; ni < 4; ++ni)
            acc[mi][ni] = __builtin_amdgcn_mfma_f32_16x16x32_f16(af[mi], bf[ni], acc[mi][ni], 0, 0, 0);
      }
    } else {
#pragma unroll
      for (int kf = 0; kf < 2; ++kf) {
        int kbyte = kf * 64 + lg * 16;
        f16x8 af[4], bf[4];
#pragma unroll
        for (int mi = 0; mi < 4; ++mi) {
          int row = wm * 64 + mi * 16 + lc;
          af[mi] = *(const f16x8*)(Ab + row * 128 + (kbyte ^ ((row & 7) << 4)));
        }
#pragma unroll
        for (int ni = 0; ni < 4; ++ni) {
          int row = wn * 64 + ni * 16 + lc;
          bf[ni] = *(const f16x8*)(Bb + row * 128 + (kbyte ^ ((row & 7) << 4)));
        }
        // swapped: C[token-row][channel-col] -> stores along n
#pragma unroll
        for (int mi = 0; mi < 4; ++mi)
#pragma unroll
          for (int ni = 0; ni < 4; ++ni)
            acc[mi][ni] = __builtin_amdgcn_mfma_f32_16x16x32_f16(bf[ni], af[mi], acc[mi][ni], 0, 0, 0);
      }
    }
    if (ks + 1 < 8)
      asm volatile("s_waitcnt vmcnt(0)\n\ts_barrier" ::: "memory");
  }

  if (mode < 2) {
    const float* bias = (mode == 0) ? bq : bk;
    int dofs = (mode == 0) ? 64 : 0;
#pragma unroll
    for (int mi = 0; mi < 4; ++mi) {
      int ch0 = o0 + wm * 64 + mi * 16 + 4 * lg - mode * 512;  // 4 consecutive channels
      int hh_ = ch0 >> 6, d0 = ch0 & 63;
#pragma unroll
      for (int ni = 0; ni < 4; ++ni) {
        int j = j0 + wn * 64 + ni * 16 + lc;
        int b = j >> 10, n = j & 1023;
        f16x4 wv;
#pragma unroll
        for (int r = 0; r < 4; ++r) {
          float y = acc[mi][ni][r] + bias[ch0 + r];
          if (mode == 1) y *= LOG2E;
          wv[r] = (_Float16)y;
        }
        *(f16x4*)(kext + ((((size_t)b * 8 + hh_) * 1024 + n) * 128) + d0 + dofs) = wv;
      }
    }
  } else {
#pragma unroll
    for (int mi = 0; mi < 4; ++mi) {
      int ch = o0 + wm * 64 + mi * 16 + lc - 1024;  // this thread's channel (col=lc)
      int hh_ = ch >> 6, d0 = ch & 63;
      float bias_v = bv[ch];
#pragma unroll
      for (int ni = 0; ni < 4; ++ni) {
        int jt = j0 + wn * 64 + ni * 16 + 4 * lg;   // 4 consecutive tokens
        int b = jt >> 10, n = jt & 1023;
        f16x4 wv;
#pragma unroll
        for (int r = 0; r < 4; ++r) wv[r] = (_Float16)(acc[mi][ni][r] + bias_v);
        *(f16x4*)(vv + (((size_t)b * 8 + hh_) * 64 + d0) * 1024 + n) = wv;
      }
    }
  }
}

// ---------------- fused flash attention + residual ---------------------------------
// R17 champion: KVBLK=64, V-hoisted oldest (vmcnt hazard fix), 2-buffer dbuf,
// vmcnt(0)/tile, lb(256,2), single sched_barrier.
__global__ __launch_bounds__(256, 2) void attn_kernel(
    const _Float16* __restrict__ kext, const _Float16* __restrict__ vv,
    const _Float16* __restrict__ post,
    const float* __restrict__ x, float* __restrict__ out) {
  __shared__ _Float16 Ke[2][8192];   // 64 rows x 256B, 16B-chunk rotation (c+row)&15
  int bid = blockIdx.x;
  int bh = bid & 127, qb = bid >> 7;   // same-bh blocks share XCD
  int b = bh >> 3, h = bh & 7;
  int t = threadIdx.x, l = t & 63;
  int lw = l & 31, hh = l >> 5;        // q-col lane, lane-half
  const _Float16* keg = kext + (size_t)bh * (1024 * 128);
  const _Float16* vbh = vv + (size_t)bh * 65536;
  const _Float16* ph = post + (size_t)h * 65536;
  int q0 = qb * 128 + (t >> 6) * 32;
  int qq = q0 + lw;

  // Q-ext B-frags: B[k = 16*kk + 8*hh + j][q = lw], resident all kernel (32 VGPR)
  f16x8 aq[8];
#pragma unroll
  for (int kk = 0; kk < 8; ++kk) {
    const _Float16* src = (kk < 4)
        ? keg + (size_t)qq * 128 + 64 + kk * 16 + hh * 8
        : ph + (size_t)qq * 64 + (kk - 4) * 16 + hh * 8;
    aq[kk] = *(const f16x8*)src;
  }

  // precomputed K ds-read byte offsets; subtile B adds 8192 (imm)
  u32 dsoff[8];
#pragma unroll
  for (int kk = 0; kk < 8; ++kk)
    dsoff[kk] = (u32)(lw * 256 + (((2 * kk + hh + lw) & 15) << 4));

  const _Float16* vb0 = vbh + (size_t)lw * 1024 + 8 * hh;
  const _Float16* vb1 = vb0 + 32 * 1024;

  float m_r = -1e30f, l_r = 0.f;
  f32x16 oaccA[2], oaccB[2];
  oaccA[0] = (f32x16)(0.f); oaccA[1] = (f32x16)(0.f);
  oaccB[0] = (f32x16)(0.f); oaccB[1] = (f32x16)(0.f);

  int srow = t >> 4, spc = t & 15;

  auto stage = [&](char* dst, int mt) {
    int m0 = mt << 6;
#pragma unroll
    for (int p = 0; p < 4; ++p) {
      int row = p * 16 + srow;
      int c = (spc - row) & 15;
      gll16(keg + (size_t)(m0 + row) * 128 + c * 8, dst + (size_t)(p * 256 + t) * 16);
    }
  };

  auto compute = [&](const char* cur, f16x8 va[2][2][2]) {
    // QK^T-ext: two independent chains (subtile A: m0..31, B: m32..63)
    f32x16 sA = (f32x16)(0.f), sB = (f32x16)(0.f);
    __builtin_amdgcn_s_setprio(1);
#pragma unroll
    for (int kk = 0; kk < 8; ++kk) {
      f16x8 kfA = *(const f16x8*)(cur + dsoff[kk]);
      f16x8 kfB = *(const f16x8*)(cur + 8192 + dsoff[kk]);
      sA = __builtin_amdgcn_mfma_f32_32x32x16_f16(kfA, aq[kk], sA, 0, 0, 0);
      sB = __builtin_amdgcn_mfma_f32_32x32x16_f16(kfB, aq[kk], sB, 0, 0, 0);
    }
    __builtin_amdgcn_s_setprio(0);

    // joint online softmax over 64 m (log2 domain), defer-rescale THR=8
    float mA0 = fmaxf(fmaxf(sA[0], sA[1]), sA[2]);
    float mA1 = fmaxf(fmaxf(sA[3], sA[4]), sA[5]);
    float mA2 = fmaxf(fmaxf(sA[6], sA[7]), sA[8]);
    float mA3 = fmaxf(fmaxf(sA[9], sA[10]), sA[11]);
    float mA4 = fmaxf(fmaxf(sA[12], sA[13]), sA[14]);
    float mB0 = fmaxf(fmaxf(sB[0], sB[1]), sB[2]);
    float mB1 = fmaxf(fmaxf(sB[3], sB[4]), sB[5]);
    float mB2 = fmaxf(fmaxf(sB[6], sB[7]), sB[8]);
    float mB3 = fmaxf(fmaxf(sB[9], sB[10]), sB[11]);
    float mB4 = fmaxf(fmaxf(sB[12], sB[13]), sB[14]);
    float uA = fmaxf(fmaxf(fmaxf(mA0, mA1), fmaxf(mA2, mA3)), fmaxf(mA4, sA[15]));
    float uB = fmaxf(fmaxf(fmaxf(mB0, mB1), fmaxf(mB2, mB3)), fmaxf(mB4, sB[15]));
    float mx = fmaxf(uA, uB);
    mx = fmaxf(mx, __shfl_xor(mx, 32));
    if (!__all(mx - m_r <= 8.0f)) {
      float mnew = fmaxf(m_r, mx);
      float scl = EXP2(m_r - mnew);
      l_r *= scl;
#pragma unroll
      for (int i = 0; i < 16; ++i) {
        oaccA[0][i] *= scl; oaccA[1][i] *= scl;
        oaccB[0][i] *= scl; oaccB[1][i] *= scl;
      }
      m_r = mnew;
    }
#pragma unroll
    for (int i = 0; i < 16; ++i) { sA[i] = EXP2(sA[i] - m_r); sB[i] = EXP2(sB[i] - m_r); }
    float aa0 = (sA[0] + sA[1]) + (sA[2] + sA[3]);
    float aa1 = (sA[4] + sA[5]) + (sA[6] + sA[7]);
    float aa2 = (sA[8] + sA[9]) + (sA[10] + sA[11]);
    float aa3 = (sA[12] + sA[13]) + (sA[14] + sA[15]);
    float bb0 = (sB[0] + sB[1]) + (sB[2] + sB[3]);
    float bb1 = (sB[4] + sB[5]) + (sB[6] + sB[7]);
    float bb2 = (sB[8] + sB[9]) + (sB[10] + sB[11]);
    float bb3 = (sB[12] + sB[13]) + (sB[14] + sB[15]);
    float rs = ((aa0 + aa1) + (aa2 + aa3)) + ((bb0 + bb1) + (bb2 + bb3));
    rs += __shfl_xor(rs, 32);
    l_r += rs;

    u32 uloA[4], uhiA[4], uloB[4], uhiB[4];
#pragma unroll
    for (int g = 0; g < 4; ++g) {
      uloA[g] = __builtin_bit_cast(u32, __builtin_amdgcn_cvt_pkrtz(sA[4 * g], sA[4 * g + 1]));
      uhiA[g] = __builtin_bit_cast(u32, __builtin_amdgcn_cvt_pkrtz(sA[4 * g + 2], sA[4 * g + 3]));
      uloB[g] = __builtin_bit_cast(u32, __builtin_amdgcn_cvt_pkrtz(sB[4 * g], sB[4 * g + 1]));
      uhiB[g] = __builtin_bit_cast(u32, __builtin_amdgcn_cvt_pkrtz(sB[4 * g + 2], sB[4 * g + 3]));
    }

    // PV: 4 independent chains (A/B x dstrip), B-frags via permlane32_swap
    __builtin_amdgcn_s_setprio(1);
#pragma unroll
    for (int p = 0; p < 2; ++p) {
      u32 A0 = uloA[2 * p], A1 = uloA[2 * p + 1];
      u32 A2 = uhiA[2 * p], A3 = uhiA[2 * p + 1];
      asm("v_permlane32_swap_b32 %0, %1" : "+v"(A0), "+v"(A1));
      asm("v_permlane32_swap_b32 %0, %1" : "+v"(A2), "+v"(A3));
      f16x8 pbA = __builtin_bit_cast(f16x8, (u32x4){A0, A2, A1, A3});
      u32 B0 = uloB[2 * p], B1 = uloB[2 * p + 1];
      u32 B2 = uhiB[2 * p], B3 = uhiB[2 * p + 1];
      asm("v_permlane32_swap_b32 %0, %1" : "+v"(B0), "+v"(B1));
      asm("v_permlane32_swap_b32 %0, %1" : "+v"(B2), "+v"(B3));
      f16x8 pbB = __builtin_bit_cast(f16x8, (u32x4){B0, B2, B1, B3});
      oaccA[0] = __builtin_amdgcn_mfma_f32_32x32x16_f16(va[0][p][0], pbA, oaccA[0], 0, 0, 0);
      oaccA[1] = __builtin_amdgcn_mfma_f32_32x32x16_f16(va[0][p][1], pbA, oaccA[1], 0, 0, 0);
      oaccB[0] = __builtin_amdgcn_mfma_f32_32x32x16_f16(va[1][p][0], pbB, oaccB[0], 0, 0, 0);
      oaccB[1] = __builtin_amdgcn_mfma_f32_32x32x16_f16(va[1][p][1], pbB, oaccB[1], 0, 0, 0);
    }
    __builtin_amdgcn_s_setprio(0);
  };

  stage((char*)Ke[0], 0);
  asm volatile("s_waitcnt vmcnt(0)\n\ts_barrier" ::: "memory");
  for (int mt = 0; mt < 16; ++mt) {
    // V A-frags FIRST (oldest VMEM this tile): PV's V-wait never drains staging
    f16x8 va[2][2][2];  // [s][p][dstrip]
#pragma unroll
    for (int s = 0; s < 2; ++s)
#pragma unroll
      for (int p = 0; p < 2; ++p) {
        va[s][p][0] = *(const f16x8*)(vb0 + mt * 64 + s * 32 + p * 16);
        va[s][p][1] = *(const f16x8*)(vb1 + mt * 64 + s * 32 + p * 16);
      }
    __builtin_amdgcn_sched_barrier(0);   // pin: V loads issued before anything younger
    if (mt + 1 < 16) stage((char*)Ke[(mt + 1) & 1], mt + 1);
    compute((const char*)Ke[mt & 1], va);
    if (mt + 1 < 16)
      asm volatile("s_waitcnt vmcnt(0)\n\ts_barrier" ::: "memory");
  }

  // epilogue: C row = (reg&3)+8*(reg>>2)+4*hh -> d = 32ds+8g+4hh+rr; q=qq
  float inv = 1.0f / l_r;
#pragma unroll
  for (int ds = 0; ds < 2; ++ds)
#pragma unroll
    for (int g = 0; g < 4; ++g)
#pragma unroll
      for (int rr = 0; rr < 4; ++rr) {
        int d = ds * 32 + g * 8 + 4 * hh + rr;
        size_t off = ((size_t)b * 512 + h * 64 + d) * 1024 + qq;
        out[off] = (oaccA[ds][g * 4 + rr] + oaccB[ds][g * 4 + rr]) * inv + x[off];
      }
}

extern "C" void kernel_launch(void* const* d_in, const int* in_sizes, int n_in,
                              void* d_out, int out_size, void* d_ws, size_t ws_size,
                              hipStream_t stream) {
  (void)in_sizes; (void)n_in; (void)out_size; (void)ws_size;
  const float* x = (const float*)d_in[0];
  const float* Wq = (const float*)d_in[1];
  const float* bq = (const float*)d_in[2];
  const float* Wk = (const float*)d_in[3];
  const float* bk = (const float*)d_in[4];
  const float* Wv = (const float*)d_in[5];
  const float* bv = (const float*)d_in[6];
  const float* rel_h = (const float*)d_in[7];
  const float* rel_w = (const float*)d_in[8];
  float* out = (float*)d_out;

  char* ws = (char*)d_ws;
  _Float16* Xt   = (_Float16*)(ws);                          // 16 MiB
  _Float16* Wall = (_Float16*)(ws + (16u << 20));            // 1.5 MiB
  _Float16* post = (_Float16*)(ws + (18u << 20));            // 1 MiB
  _Float16* Kext = (_Float16*)(ws + (19u << 20));            // 32 MiB
  _Float16* vw   = (_Float16*)(ws + (51u << 20));            // 16 MiB

  hipLaunchKernelGGL(transpose_prep_kernel, dim3(2048), dim3(256), 0, stream,
                     x, Xt, Wq, Wk, Wv, rel_h, rel_w, Wall, post);
  hipLaunchKernelGGL(qkv_gemm, dim3(1536), dim3(256), 0, stream,
                     Wall, Xt, bq, bk, bv, Kext, vw);
  hipLaunchKernelGGL(attn_kernel, dim3(1024), dim3(256), 0, stream,
                     Kext, vw, post, x, out);
}

// Round 20
// 149.689 us; speedup vs baseline: 1.0186x; 1.0186x over previous
//
#include <hip/hip_runtime.h>
#include <hip/hip_bf16.h>

typedef _Float16 f16x8 __attribute__((ext_vector_type(8)));
typedef _Float16 f16x4 __attribute__((ext_vector_type(4)));
typedef float f32x4 __attribute__((ext_vector_type(4)));
typedef float f32x16 __attribute__((ext_vector_type(16)));
typedef unsigned int u32;
typedef u32 u32x4 __attribute__((ext_vector_type(4)));

#define LOG2E 1.4426950408889634f

#if __has_builtin(__builtin_amdgcn_exp2f)
#define EXP2(x) __builtin_amdgcn_exp2f(x)
#else
__device__ inline float EXP2(float x) { float r; asm("v_exp_f32 %0, %1\n\ts_nop 0" : "=v"(r) : "v"(x)); return r; }
#endif

// B=16, C=512, HEAD=8, D=64, N=1024 (W=H=32)

__device__ inline void gll16(const void* g, void* l) {
  __builtin_amdgcn_global_load_lds(
      (const __attribute__((address_space(1))) void*)g,
      (__attribute__((address_space(3))) void*)l, 16, 0, 0);
}

// ---------------- transpose + prep fused ----------------
__global__ __launch_bounds__(256) void transpose_prep_kernel(
    const float* __restrict__ x, _Float16* __restrict__ Xt,
    const float* __restrict__ Wq, const float* __restrict__ Wk, const float* __restrict__ Wv,
    const float* __restrict__ rel_h, const float* __restrict__ rel_w,
    _Float16* __restrict__ Wall, _Float16* __restrict__ post) {
  __shared__ float tl[64][65];
  int bid = blockIdx.x;
  int b = bid >> 7;
  int rem = bid & 127;
  int c0 = (rem >> 4) * 64;
  int n0 = (rem & 15) * 64;
  int t = threadIdx.x;
#pragma unroll
  for (int p = 0; p < 16; ++p) {
    int idx = p * 256 + t;
    int i = idx >> 6, j = idx & 63;
    tl[i][j] = x[((size_t)b * 512 + c0 + i) * 1024 + n0 + j];
  }
  __syncthreads();
#pragma unroll
  for (int p = 0; p < 16; ++p) {
    int idx = p * 256 + t;
    int j = idx >> 6, i = idx & 63;
    Xt[((size_t)b * 1024 + n0 + j) * 512 + c0 + i] = (_Float16)tl[i][j];
  }
  for (int idx = bid * 256 + t; idx < 1310720; idx += 524288) {
    if (idx < 1536 * 512) {
      int o = idx >> 9;
      float wv;
      if (o < 512) wv = Wq[idx];
      else if (o < 1024) wv = Wk[idx - 512 * 512];
      else wv = Wv[idx - 1024 * 512];
      Wall[idx] = (_Float16)wv;
    } else {
      int p = idx - 1536 * 512;            // [0, 8*1024*64)
      int h = p >> 16;
      int rm = p & 65535;
      int n = rm >> 6;
      int d = rm & 63;
      float v = rel_h[(h * 64 + d) * 32 + (n & 31)] + rel_w[(h * 64 + d) * 32 + (n >> 5)];
      post[p] = (_Float16)(v * LOG2E);
    }
  }
}

// ---------------- QKV projection GEMM (double-buffered, 1 barrier/K-step) ----------
// writes Kext[b][h][n][0:64]=k*log2e, [64:128]=q ; v[b][h][d][n]  (f16)
__global__ __launch_bounds__(256) void qkv_gemm(
    const _Float16* __restrict__ Wall, const _Float16* __restrict__ Xt,
    const float* __restrict__ bq, const float* __restrict__ bk, const float* __restrict__ bv,
    _Float16* __restrict__ kext, _Float16* __restrict__ vv) {
  __shared__ _Float16 At[2][128 * 64];
  __shared__ _Float16 Bt[2][128 * 64];
  int bid = blockIdx.x;
  int mb = bid >> 7, nb = bid & 127;
  int o0 = mb * 128, j0 = nb * 128;
  int t = threadIdx.x;
  int w = t >> 6, l = t & 63, lg = l >> 4, lc = l & 15;
  int wm = w >> 1, wn = w & 1;
  int mode = mb >> 2;  // 0=q, 1=k, 2=v (block-uniform)
  f32x4 acc[4][4];
#pragma unroll
  for (int a = 0; a < 4; ++a)
#pragma unroll
    for (int bb = 0; bb < 4; ++bb) acc[a][bb] = (f32x4){0.f, 0.f, 0.f, 0.f};

  auto stageg = [&](int bufi, int k0) {
#pragma unroll
    for (int p = 0; p < 4; ++p) {
      int li = p * 256 + t;            // 16B chunk index
      int row = li >> 3;               // tile row
      int colb = (li & 7) << 4;        // linear byte col in row
      int scol = (colb ^ ((row & 7) << 4)) >> 1;  // inverse-swizzled f16 col
      gll16(Wall + (size_t)(o0 + row) * 512 + k0 + scol, At[bufi] + (size_t)li * 8);
      gll16(Xt + (size_t)(j0 + row) * 512 + k0 + scol, Bt[bufi] + (size_t)li * 8);
    }
  };

  stageg(0, 0);
  asm volatile("s_waitcnt vmcnt(0)\n\ts_barrier" ::: "memory");
  for (int ks = 0; ks < 8; ++ks) {
    if (ks + 1 < 8) stageg((ks + 1) & 1, (ks + 1) * 64);
    const char* Ab = (const char*)At[ks & 1];
    const char* Bb = (const char*)Bt[ks & 1];
    if (mode < 2) {
#pragma unroll
      for (int kf = 0; kf < 2; ++kf) {
        int kbyte = kf * 64 + lg * 16;
        f16x8 af[4], bf[4];
#pragma unroll
        for (int mi = 0; mi < 4; ++mi) {
          int row = wm * 64 + mi * 16 + lc;
          af[mi] = *(const f16x8*)(Ab + row * 128 + (kbyte ^ ((row & 7) << 4)));
        }
#pragma unroll
        for (int ni = 0; ni < 4; ++ni) {
          int row = wn * 64 + ni * 16 + lc;
          bf[ni] = *(const f16x8*)(Bb + row * 128 + (kbyte ^ ((row & 7) << 4)));
        }
#pragma unroll
        for (int mi = 0; mi < 4; ++mi)
#pragma unroll
          for (int ni = 0; ni < 4; ++ni)
            acc[mi][ni] = __builtin_amdgcn_mfma_f32_16x16x32_f16(af[mi], bf[ni], acc[mi][ni], 0, 0, 0);
      }
    } else {
#pragma unroll
      for (int kf = 0; kf < 2; ++kf) {
        int kbyte = kf * 64 + lg * 16;
        f16x8 af[4], bf[4];
#pragma unroll
        for (int mi = 0; mi < 4; ++mi) {
          int row = wm * 64 + mi * 16 + lc;
          af[mi] = *(const f16x8*)(Ab + row * 128 + (kbyte ^ ((row & 7) << 4)));
        }
#pragma unroll
        for (int ni = 0; ni < 4; ++ni) {
          int row = wn * 64 + ni * 16 + lc;
          bf[ni] = *(const f16x8*)(Bb + row * 128 + (kbyte ^ ((row & 7) << 4)));
        }
        // swapped: C[token-row][channel-col] -> stores along n
#pragma unroll
        for (int mi = 0; mi < 4; ++mi)
#pragma unroll
          for (int ni = 0; ni < 4; ++ni)
            acc[mi][ni] = __builtin_amdgcn_mfma_f32_16x16x32_f16(bf[ni], af[mi], acc[mi][ni], 0, 0, 0);
      }
    }
    if (ks + 1 < 8)
      asm volatile("s_waitcnt vmcnt(0)\n\ts_barrier" ::: "memory");
  }

  if (mode < 2) {
    const float* bias = (mode == 0) ? bq : bk;
    int dofs = (mode == 0) ? 64 : 0;
#pragma unroll
    for (int mi = 0; mi < 4; ++mi) {
      int ch0 = o0 + wm * 64 + mi * 16 + 4 * lg - mode * 512;  // 4 consecutive channels
      int hh_ = ch0 >> 6, d0 = ch0 & 63;
#pragma unroll
      for (int ni = 0; ni < 4; ++ni) {
        int j = j0 + wn * 64 + ni * 16 + lc;
        int b = j >> 10, n = j & 1023;
        f16x4 wv;
#pragma unroll
        for (int r = 0; r < 4; ++r) {
          float y = acc[mi][ni][r] + bias[ch0 + r];
          if (mode == 1) y *= LOG2E;
          wv[r] = (_Float16)y;
        }
        *(f16x4*)(kext + ((((size_t)b * 8 + hh_) * 1024 + n) * 128) + d0 + dofs) = wv;
      }
    }
  } else {
#pragma unroll
    for (int mi = 0; mi < 4; ++mi) {
      int ch = o0 + wm * 64 + mi * 16 + lc - 1024;  // this thread's channel (col=lc)
      int hh_ = ch >> 6, d0 = ch & 63;
      float bias_v = bv[ch];
#pragma unroll
      for (int ni = 0; ni < 4; ++ni) {
        int jt = j0 + wn * 64 + ni * 16 + 4 * lg;   // 4 consecutive tokens
        int b = jt >> 10, n = jt & 1023;
        f16x4 wv;
#pragma unroll
        for (int r = 0; r < 4; ++r) wv[r] = (_Float16)(acc[mi][ni][r] + bias_v);
        *(f16x4*)(vv + (((size_t)b * 8 + hh_) * 64 + d0) * 1024 + n) = wv;
      }
    }
  }
}

// ---------------- fused flash attention + residual ---------------------------------
// Champion (R17): KVBLK=64, V-hoisted oldest (vmcnt hazard fix), 2-buffer dbuf,
// vmcnt(0)/tile, lb(256,2), single sched_barrier.
__global__ __launch_bounds__(256, 2) void attn_kernel(
    const _Float16* __restrict__ kext, const _Float16* __restrict__ vv,
    const _Float16* __restrict__ post,
    const float* __restrict__ x, float* __restrict__ out) {
  __shared__ _Float16 Ke[2][8192];   // 64 rows x 256B, 16B-chunk rotation (c+row)&15
  int bid = blockIdx.x;
  int bh = bid & 127, qb = bid >> 7;   // same-bh blocks share XCD
  int b = bh >> 3, h = bh & 7;
  int t = threadIdx.x, l = t & 63;
  int lw = l & 31, hh = l >> 5;        // q-col lane, lane-half
  const _Float16* keg = kext + (size_t)bh * (1024 * 128);
  const _Float16* vbh = vv + (size_t)bh * 65536;
  const _Float16* ph = post + (size_t)h * 65536;
  int q0 = qb * 128 + (t >> 6) * 32;
  int qq = q0 + lw;

  // Q-ext B-frags: B[k = 16*kk + 8*hh + j][q = lw], resident all kernel (32 VGPR)
  f16x8 aq[8];
#pragma unroll
  for (int kk = 0; kk < 8; ++kk) {
    const _Float16* src = (kk < 4)
        ? keg + (size_t)qq * 128 + 64 + kk * 16 + hh * 8
        : ph + (size_t)qq * 64 + (kk - 4) * 16 + hh * 8;
    aq[kk] = *(const f16x8*)src;
  }

  // precomputed K ds-read byte offsets; subtile B adds 8192 (imm)
  u32 dsoff[8];
#pragma unroll
  for (int kk = 0; kk < 8; ++kk)
    dsoff[kk] = (u32)(lw * 256 + (((2 * kk + hh + lw) & 15) << 4));

  const _Float16* vb0 = vbh + (size_t)lw * 1024 + 8 * hh;
  const _Float16* vb1 = vb0 + 32 * 1024;

  float m_r = -1e30f, l_r = 0.f;
  f32x16 oaccA[2], oaccB[2];
  oaccA[0] = (f32x16)(0.f); oaccA[1] = (f32x16)(0.f);
  oaccB[0] = (f32x16)(0.f); oaccB[1] = (f32x16)(0.f);

  int srow = t >> 4, spc = t & 15;

  auto stage = [&](char* dst, int mt) {
    int m0 = mt << 6;
#pragma unroll
    for (int p = 0; p < 4; ++p) {
      int row = p * 16 + srow;
      int c = (spc - row) & 15;
      gll16(keg + (size_t)(m0 + row) * 128 + c * 8, dst + (size_t)(p * 256 + t) * 16);
    }
  };

  auto compute = [&](const char* cur, f16x8 va[2][2][2]) {
    // QK^T-ext: two independent chains (subtile A: m0..31, B: m32..63)
    f32x16 sA = (f32x16)(0.f), sB = (f32x16)(0.f);
    __builtin_amdgcn_s_setprio(1);
#pragma unroll
    for (int kk = 0; kk < 8; ++kk) {
      f16x8 kfA = *(const f16x8*)(cur + dsoff[kk]);
      f16x8 kfB = *(const f16x8*)(cur + 8192 + dsoff[kk]);
      sA = __builtin_amdgcn_mfma_f32_32x32x16_f16(kfA, aq[kk], sA, 0, 0, 0);
      sB = __builtin_amdgcn_mfma_f32_32x32x16_f16(kfB, aq[kk], sB, 0, 0, 0);
    }
    __builtin_amdgcn_s_setprio(0);

    // joint online softmax over 64 m (log2 domain), defer-rescale THR=8
    float mA0 = fmaxf(fmaxf(sA[0], sA[1]), sA[2]);
    float mA1 = fmaxf(fmaxf(sA[3], sA[4]), sA[5]);
    float mA2 = fmaxf(fmaxf(sA[6], sA[7]), sA[8]);
    float mA3 = fmaxf(fmaxf(sA[9], sA[10]), sA[11]);
    float mA4 = fmaxf(fmaxf(sA[12], sA[13]), sA[14]);
    float mB0 = fmaxf(fmaxf(sB[0], sB[1]), sB[2]);
    float mB1 = fmaxf(fmaxf(sB[3], sB[4]), sB[5]);
    float mB2 = fmaxf(fmaxf(sB[6], sB[7]), sB[8]);
    float mB3 = fmaxf(fmaxf(sB[9], sB[10]), sB[11]);
    float mB4 = fmaxf(fmaxf(sB[12], sB[13]), sB[14]);
    float uA = fmaxf(fmaxf(fmaxf(mA0, mA1), fmaxf(mA2, mA3)), fmaxf(mA4, sA[15]));
    float uB = fmaxf(fmaxf(fmaxf(mB0, mB1), fmaxf(mB2, mB3)), fmaxf(mB4, sB[15]));
    float mx = fmaxf(uA, uB);
    mx = fmaxf(mx, __shfl_xor(mx, 32));
    if (!__all(mx - m_r <= 8.0f)) {
      float mnew = fmaxf(m_r, mx);
      float scl = EXP2(m_r - mnew);
      l_r *= scl;
#pragma unroll
      for (int i = 0; i < 16; ++i) {
        oaccA[0][i] *= scl; oaccA[1][i] *= scl;
        oaccB[0][i] *= scl; oaccB[1][i] *= scl;
      }
      m_r = mnew;
    }
#pragma unroll
    for (int i = 0; i < 16; ++i) { sA[i] = EXP2(sA[i] - m_r); sB[i] = EXP2(sB[i] - m_r); }
    float aa0 = (sA[0] + sA[1]) + (sA[2] + sA[3]);
    float aa1 = (sA[4] + sA[5]) + (sA[6] + sA[7]);
    float aa2 = (sA[8] + sA[9]) + (sA[10] + sA[11]);
    float aa3 = (sA[12] + sA[13]) + (sA[14] + sA[15]);
    float bb0 = (sB[0] + sB[1]) + (sB[2] + sB[3]);
    float bb1 = (sB[4] + sB[5]) + (sB[6] + sB[7]);
    float bb2 = (sB[8] + sB[9]) + (sB[10] + sB[11]);
    float bb3 = (sB[12] + sB[13]) + (sB[14] + sB[15]);
    float rs = ((aa0 + aa1) + (aa2 + aa3)) + ((bb0 + bb1) + (bb2 + bb3));
    rs += __shfl_xor(rs, 32);
    l_r += rs;

    u32 uloA[4], uhiA[4], uloB[4], uhiB[4];
#pragma unroll
    for (int g = 0; g < 4; ++g) {
      uloA[g] = __builtin_bit_cast(u32, __builtin_amdgcn_cvt_pkrtz(sA[4 * g], sA[4 * g + 1]));
      uhiA[g] = __builtin_bit_cast(u32, __builtin_amdgcn_cvt_pkrtz(sA[4 * g + 2], sA[4 * g + 3]));
      uloB[g] = __builtin_bit_cast(u32, __builtin_amdgcn_cvt_pkrtz(sB[4 * g], sB[4 * g + 1]));
      uhiB[g] = __builtin_bit_cast(u32, __builtin_amdgcn_cvt_pkrtz(sB[4 * g + 2], sB[4 * g + 3]));
    }

    // PV: 4 independent chains (A/B x dstrip), B-frags via permlane32_swap
    __builtin_amdgcn_s_setprio(1);
#pragma unroll
    for (int p = 0; p < 2; ++p) {
      u32 A0 = uloA[2 * p], A1 = uloA[2 * p + 1];
      u32 A2 = uhiA[2 * p], A3 = uhiA[2 * p + 1];
      asm("v_permlane32_swap_b32 %0, %1" : "+v"(A0), "+v"(A1));
      asm("v_permlane32_swap_b32 %0, %1" : "+v"(A2), "+v"(A3));
      f16x8 pbA = __builtin_bit_cast(f16x8, (u32x4){A0, A2, A1, A3});
      u32 B0 = uloB[2 * p], B1 = uloB[2 * p + 1];
      u32 B2 = uhiB[2 * p], B3 = uhiB[2 * p + 1];
      asm("v_permlane32_swap_b32 %0, %1" : "+v"(B0), "+v"(B1));
      asm("v_permlane32_swap_b32 %0, %1" : "+v"(B2), "+v"(B3));
      f16x8 pbB = __builtin_bit_cast(f16x8, (u32x4){B0, B2, B1, B3});
      oaccA[0] = __builtin_amdgcn_mfma_f32_32x32x16_f16(va[0][p][0], pbA, oaccA[0], 0, 0, 0);
      oaccA[1] = __builtin_amdgcn_mfma_f32_32x32x16_f16(va[0][p][1], pbA, oaccA[1], 0, 0, 0);
      oaccB[0] = __builtin_amdgcn_mfma_f32_32x32x16_f16(va[1][p][0], pbB, oaccB[0], 0, 0, 0);
      oaccB[1] = __builtin_amdgcn_mfma_f32_32x32x16_f16(va[1][p][1], pbB, oaccB[1], 0, 0, 0);
    }
    __builtin_amdgcn_s_setprio(0);
  };

  stage((char*)Ke[0], 0);
  asm volatile("s_waitcnt vmcnt(0)\n\ts_barrier" ::: "memory");
  for (int mt = 0; mt < 16; ++mt) {
    // V A-frags FIRST (oldest VMEM this tile): PV's V-wait never drains staging
    f16x8 va[2][2][2];  // [s][p][dstrip]
#pragma unroll
    for (int s = 0; s < 2; ++s)
#pragma unroll
      for (int p = 0; p < 2; ++p) {
        va[s][p][0] = *(const f16x8*)(vb0 + mt * 64 + s * 32 + p * 16);
        va[s][p][1] = *(const f16x8*)(vb1 + mt * 64 + s * 32 + p * 16);
      }
    __builtin_amdgcn_sched_barrier(0);   // pin: V loads issued before anything younger
    if (mt + 1 < 16) stage((char*)Ke[(mt + 1) & 1], mt + 1);
    compute((const char*)Ke[mt & 1], va);
    if (mt + 1 < 16)
      asm volatile("s_waitcnt vmcnt(0)\n\ts_barrier" ::: "memory");
  }

  // epilogue: C row = (reg&3)+8*(reg>>2)+4*hh -> d = 32ds+8g+4hh+rr; q=qq
  float inv = 1.0f / l_r;
#pragma unroll
  for (int ds = 0; ds < 2; ++ds)
#pragma unroll
    for (int g = 0; g < 4; ++g)
#pragma unroll
      for (int rr = 0; rr < 4; ++rr) {
        int d = ds * 32 + g * 8 + 4 * hh + rr;
        size_t off = ((size_t)b * 512 + h * 64 + d) * 1024 + qq;
        out[off] = (oaccA[ds][g * 4 + rr] + oaccB[ds][g * 4 + rr]) * inv + x[off];
      }
}

extern "C" void kernel_launch(void* const* d_in, const int* in_sizes, int n_in,
                              void* d_out, int out_size, void* d_ws, size_t ws_size,
                              hipStream_t stream) {
  (void)in_sizes; (void)n_in; (void)out_size; (void)ws_size;
  const float* x = (const float*)d_in[0];
  const float* Wq = (const float*)d_in[1];
  const float* bq = (const float*)d_in[2];
  const float* Wk = (const float*)d_in[3];
  const float* bk = (const float*)d_in[4];
  const float* Wv = (const float*)d_in[5];
  const float* bv = (const float*)d_in[6];
  const float* rel_h = (const float*)d_in[7];
  const float* rel_w = (const float*)d_in[8];
  float* out = (float*)d_out;

  char* ws = (char*)d_ws;
  _Float16* Xt   = (_Float16*)(ws);                          // 16 MiB
  _Float16* Wall = (_Float16*)(ws + (16u << 20));            // 1.5 MiB
  _Float16* post = (_Float16*)(ws + (18u << 20));            // 1 MiB
  _Float16* Kext = (_Float16*)(ws + (19u << 20));            // 32 MiB
  _Float16* vw   = (_Float16*)(ws + (51u << 20));            // 16 MiB

  hipLaunchKernelGGL(transpose_prep_kernel, dim3(2048), dim3(256), 0, stream,
                     x, Xt, Wq, Wk, Wv, rel_h, rel_w, Wall, post);
  hipLaunchKernelGGL(qkv_gemm, dim3(1536), dim3(256), 0, stream,
                     Wall, Xt, bq, bk, bv, Kext, vw);
  hipLaunchKernelGGL(attn_kernel, dim3(1024), dim3(256), 0, stream,
                     Kext, vw, post, x, out);
}